// Round 18
// baseline (303.226 us; speedup 1.0000x reference)
//
#include <hip/hip_runtime.h>
#include <hip/hip_bf16.h>

#define BB 2
#define NN 2048
#define DD 128
#define BN (BB*NN)
#define CAP 128
#define TD 32
#define CCAP 32
#define QSTR 256
#define SSTR 128
#define INV_SQRT_D 0.08838834764831845f

typedef __attribute__((ext_vector_type(8))) short short8;
typedef __attribute__((ext_vector_type(4))) float f32x4;

__device__ inline float b2f(unsigned short u) {
    union { unsigned int i; float f; } c; c.i = (unsigned int)u << 16; return c.f;
}
__device__ inline float b2f_hi(unsigned int raw) {
    union { unsigned int i; float f; } c; c.i = raw & 0xffff0000u; return c.f;
}
__device__ inline float b2f_lo(unsigned int raw) {
    union { unsigned int i; float f; } c; c.i = raw << 16; return c.f;
}

// 16-lane sum, VALU-only (DPP): quad xor1, quad xor2, row_ror:4, row_ror:8.
__device__ inline float dpp_sum16(float x) {
    int v;
    v = __builtin_bit_cast(int, x);
    x += __builtin_bit_cast(float, __builtin_amdgcn_update_dpp(0, v, 0xB1,  0xF, 0xF, true)); // quad_perm [1,0,3,2]
    v = __builtin_bit_cast(int, x);
    x += __builtin_bit_cast(float, __builtin_amdgcn_update_dpp(0, v, 0x4E,  0xF, 0xF, true)); // quad_perm [2,3,0,1]
    v = __builtin_bit_cast(int, x);
    x += __builtin_bit_cast(float, __builtin_amdgcn_update_dpp(0, v, 0x124, 0xF, 0xF, true)); // row_ror:4
    v = __builtin_bit_cast(int, x);
    x += __builtin_bit_cast(float, __builtin_amdgcn_update_dpp(0, v, 0x128, 0xF, 0xF, true)); // row_ror:8
    return x;
}

// wave-uniform broadcast of lane `l` (compile-time) -> SGPR, no DS op
__device__ inline float readlane_f(float x, int l) {
    return __builtin_bit_cast(float, __builtin_amdgcn_readlane(__builtin_bit_cast(int, x), l));
}

// ---------------------------------------------------------------------------
// Merged prep kernel (unchanged from round 17 — segmented CSR, no atomics,
// no memset):
//   bid < 1024         : CSR build, TD=32 dst stripes x 8 src chunks
//   1024 <= bid < 2432 : weight transposes Wt1 (512) / Wt2 (896)
//   2432 <= bid < 2688 : layer-0 rank-1 projection (256 row-tiles)
// ---------------------------------------------------------------------------
__global__ __launch_bounds__(256) void prep(
    const float* __restrict__ A, const float* __restrict__ edge,
    const float* __restrict__ node,
    const float* __restrict__ Wq0, const float* __restrict__ Wk0,
    const float* __restrict__ Wv0, const float* __restrict__ Ws0,
    const float* __restrict__ Wq1, const float* __restrict__ Wk1,
    const float* __restrict__ Wv1, const float* __restrict__ Ws1,
    const float* __restrict__ Wq2, const float* __restrict__ Wk2,
    const float* __restrict__ Wv2, const float* __restrict__ Ws2,
    __hip_bfloat16* __restrict__ Wt1, __hip_bfloat16* __restrict__ Wt2,
    float* __restrict__ q, __hip_bfloat16* __restrict__ kA,
    __hip_bfloat16* __restrict__ vA, float* __restrict__ s,
    unsigned short* __restrict__ degc,      // [BN][8]
    unsigned short* __restrict__ colsc,     // [BN][8][CCAP]
    float* __restrict__ evalsc)             // [BN][8][CCAP]
{
    __shared__ int   cnt[TD];
    __shared__ int   csh[TD][CCAP];
    __shared__ float esh[TD][CCAP];
    __shared__ float xnode[16];

    int bid = blockIdx.x;
    int tid = threadIdx.x;

    if (bid < 1024) {
        // ---- CSR build: 32 dst cols x 256 src rows per block ----
        int b     = bid >> 9;
        int r     = bid & 511;
        int dst0  = (r >> 3) * TD;
        int chunk = r & 7;

        if (tid < TD) cnt[tid] = 0;
        __syncthreads();

        int srcOff = tid >> 3;
        int dOff   = (tid & 7) * 4;
        int src0   = chunk * 256;
        const size_t base = (size_t)b * NN * NN + (size_t)src0 * NN + dst0 + dOff;

#pragma unroll 2
        for (int s0 = 0; s0 < 256; s0 += 32) {
            int srel = s0 + srcOff;
            float4 a4 = *(const float4*)&A[base + (size_t)srel * NN];
            float4 e4 = *(const float4*)&edge[base + (size_t)srel * NN];
            int gsrc = b * NN + src0 + srel;
            float av[4] = {a4.x, a4.y, a4.z, a4.w};
            float ev[4] = {e4.x, e4.y, e4.z, e4.w};
#pragma unroll
            for (int u = 0; u < 4; u++) {
                if (av[u] != 0.f) {
                    int d = dOff + u;
                    int slot = atomicAdd(&cnt[d], 1);   // LDS atomic only
                    if (slot < CCAP) { csh[d][slot] = gsrc; esh[d][slot] = ev[u] * av[u]; }
                }
            }
        }
        __syncthreads();

        if (tid < TD) {
            int row = b * NN + dst0 + tid;
            degc[(size_t)row * 8 + chunk] = (unsigned short)min(cnt[tid], CCAP);
        }

        for (int idx = tid; idx < TD * CCAP; idx += 256) {
            int d = idx >> 5, i = idx & (CCAP - 1);
            if (i < min(cnt[d], CCAP)) {
                size_t seg = ((size_t)(b * NN + dst0 + d) * 8 + chunk) * CCAP;
                colsc [seg + i] = (unsigned short)csh[d][i];
                evalsc[seg + i] = esh[d][i];
            }
        }
    } else if (bid < 1024 + 1408) {
        int c = bid - 1024;
        if (tid < DD) {
            const float *Wq, *Wk, *Wv, *Ws; __hip_bfloat16* Wt; int n, HD;
            if (c < 512) { Wq = Wq1; Wk = Wk1; Wv = Wv1; Ws = Ws1; Wt = Wt1; n = c;       HD = DD;     }
            else         { Wq = Wq2; Wk = Wk2; Wv = Wv2; Ws = Ws2; Wt = Wt2; n = c - 512; HD = 2 * DD; }
            const float* src; int ld; int col;
            if      (n < HD)     { src = Wq; col = n;          ld = HD; }
            else if (n < 2*HD)   { src = Wk; col = n - HD;     ld = HD; }
            else if (n < 3*HD)   { src = Wv; col = n - 2*HD;   ld = HD; }
            else                 { src = Ws; col = n - 3*HD;   ld = DD; }
            Wt[(size_t)n * DD + tid] = __float2bfloat16(src[(size_t)tid * ld + col]);
        }
    } else {
        int row0 = (bid - (1024 + 1408)) * 16;
        if (tid < 16) xnode[tid] = node[row0 + tid];
        __syncthreads();
        for (int i = tid; i < 16 * 512; i += 256) {
            int r = i >> 9, col = i & 511;
            float xv = xnode[r];
            if (col < DD) {
                q[(size_t)(row0 + r) * QSTR + col] = xv * Wq0[col];
            } else if (col < 2*DD) {
                int lc = col - DD;
                kA[(size_t)(row0 + r) * 256 + lc] = __float2bfloat16(xv * Wk0[lc]);
            } else if (col < 3*DD) {
                int lc = col - 2*DD;
                vA[(size_t)(row0 + r) * 256 + lc] = __float2bfloat16(xv * Wv0[lc]);
            } else {
                int lc = col - 3*DD;
                s[(size_t)(row0 + r) * SSTR + lc] = xv * Ws0[lc];
            }
        }
    }
}

// ---------------------------------------------------------------------------
// Fused sparse attention + next-layer projection — round-17 body with the
// DEGREE-TAIL fix: 8 rows per block (512 threads), grid BN/8 = 512 = 2+
// blocks/CU co-resident, so a block stalled on a high-degree row overlaps
// another block's waves (at 1 block/CU the slowest row WAS the device
// critical path: ceil(maxdeg/8) ~ 13 iters vs mean 8). Straight-line loop
// body unchanged (r7's regression was the lambda pipeline, not geometry).
// Epilogue: xs rows 8..15 zeroed, writes predicated to quads 0-1 (the
// r7-verified pattern). H=1: MINW=8 (VGPR<=64, 4 blocks/CU); H=2: MINW=4.
// ---------------------------------------------------------------------------
template<int H, int MINW, bool MEANH, bool LNRELU, int NCOLS, int HDN, int KVSI, int KVSO>
__global__ __launch_bounds__(512, MINW) void fused_attn(
    float* qio,                                   // in/out, stride QSTR
    const __hip_bfloat16* __restrict__ k,         // stride KVSI
    const __hip_bfloat16* __restrict__ v,         // stride KVSI
    float* sio,                                   // in/out, stride SSTR
    const unsigned short* __restrict__ degc,      // [BN][8]
    const unsigned short* __restrict__ colsc,     // [BN][8][CCAP]
    const float* __restrict__ evalsc,             // [BN][8][CCAP]
    const float* __restrict__ We,
    const __hip_bfloat16* __restrict__ Wt,
    __hip_bfloat16* __restrict__ kn, __hip_bfloat16* __restrict__ vn, // stride KVSO
    float* __restrict__ out)
{
    const int HD = H * DD;
    constexpr unsigned KROWB = (unsigned)(KVSI * 2);   // bytes per k/v row (512 or 256, pow2)
    int wid  = threadIdx.x >> 6;       // 0..7
    int lane = threadIdx.x & 63;
    int row0 = blockIdx.x * 8;
    int row  = row0 + wid;
    int sub  = lane >> 4;
    int s    = lane & 15;
    int c0   = lane * 2;

    __shared__ int            jc_s[8][CAP];
    __shared__ float          ev_s[8][CAP];
    __shared__ __hip_bfloat16 xs[16][136];   // rows 8..15 zero (MFMA pad)
    int*   jc = jc_s[wid];
    float* ev = ev_s[wid];

    if constexpr (NCOLS != 0) {
        short* xz = (short*)&xs[8][0];
        for (int i = threadIdx.x; i < 8 * 136; i += 512) xz[i] = 0;
    }

    // ---- segmented CSR load: counts -> prefix -> gather-compact ----
    int dg;
    {
        const unsigned short* dcp = &degc[(size_t)row * 8];
        int cnt8[8], offs[8], off = 0;
#pragma unroll
        for (int c = 0; c < 8; c++) cnt8[c] = (int)dcp[c];
#pragma unroll
        for (int c = 0; c < 8; c++) { offs[c] = off; off += cnt8[c]; }
        dg = min(off, CAP);
        const size_t segb = (size_t)row * 8 * CCAP;
#pragma unroll
        for (int it = 0; it < 4; it++) {
            int i = it * 64 + lane;
            int c = i >> 5, m = i & (CCAP - 1);
            if (m < cnt8[c]) {
                int d = offs[c] + m;
                if (d < CAP) {
                    jc[d] = (int)colsc[segb + c * CCAP + m];
                    ev[d] = evalsc[segb + c * CCAP + m];
                }
            }
        }
    }
    int dgp = (dg + 7) & ~7;             // padded bound (multiple of 8)
    if (lane == 0 && dg > 0) {
        int jf = jc[0];
        for (int m = dg; m < dgp; m++) { jc[m] = jf; ev[m] = 0.f; }
    }
    // wave-private LDS: no barrier needed (compiler inserts lgkmcnt waits)

    const char* kc = (const char*)k;
    const char* vc = (const char*)v;
    const unsigned kLaneOff = (unsigned)(s * 16);      // s*8 bf16 = 16 B
    const unsigned vLaneOff = (unsigned)(c0 * 2);      // c0 bf16 = c0*2 B

    float qh[H][8];
    float qeI[H];
#pragma unroll
    for (int h = 0; h < H; h++) {
        const float* qp = &qio[(size_t)row * QSTR + h * DD + s * 8];
        const float* wp = &We[h * DD + s * 8];
        float pe = 0.f;
#pragma unroll
        for (int t = 0; t < 8; t++) { qh[h][t] = qp[t]; pe += qp[t] * wp[t]; }
        qeI[h] = dpp_sum16(pe) * INV_SQRT_D;
    }

    float l_acc[H], ew_acc[H], acc[H][2];
#pragma unroll
    for (int h = 0; h < H; h++) { l_acc[h] = 0.f; ew_acc[h] = 0.f; acc[h][0] = 0.f; acc[h][1] = 0.f; }

    for (int m0 = 0; m0 < dgp; m0 += 8) {
        int   e0  = m0 + sub,  e1 = m0 + 4 + sub;
        bool  ok0 = e0 < dg,   ok1 = e1 < dg;
        float ee0 = ev[e0],    ee1 = ev[e1];     // pad region holds 0 (unused: alpha=0)

        // 32-bit byte offsets (KROWB is pow2 -> shift+add; no 64-bit muls)
        unsigned ko0 = (unsigned)jc[e0] * KROWB + kLaneOff;
        unsigned ko1 = (unsigned)jc[e1] * KROWB + kLaneOff;

        int4 j4a = *(const int4*)&jc[m0];        // vectorized CSR reads (pad = jc[0])
        int4 j4b = *(const int4*)&jc[m0 + 4];
        unsigned vo[8] = {
            (unsigned)j4a.x * KROWB + vLaneOff, (unsigned)j4a.y * KROWB + vLaneOff,
            (unsigned)j4a.z * KROWB + vLaneOff, (unsigned)j4a.w * KROWB + vLaneOff,
            (unsigned)j4b.x * KROWB + vLaneOff, (unsigned)j4b.y * KROWB + vLaneOff,
            (unsigned)j4b.z * KROWB + vLaneOff, (unsigned)j4b.w * KROWB + vLaneOff };

        // k gathers FIRST (consumed first by the dot; keeps v loads in flight);
        // per-h displacement (h*256 B) is a compile-time immediate
        short8 kk0[H], kk1[H];
#pragma unroll
        for (int h = 0; h < H; h++) {
            kk0[h] = *(const short8*)(kc + (size_t)(ko0 + (unsigned)(h * 256)));
            kk1[h] = *(const short8*)(kc + (size_t)(ko1 + (unsigned)(h * 256)));
        }
        // v gathers
        unsigned int vraw[H][8];
#pragma unroll
        for (int h = 0; h < H; h++)
#pragma unroll
            for (int es = 0; es < 8; es++)
                vraw[h][es] = *(const unsigned int*)(vc + (size_t)(vo[es] + (unsigned)(h * 256)));

        __builtin_amdgcn_s_setprio(1);
#pragma unroll
        for (int h = 0; h < H; h++) {
            float p0 = qh[h][0]*b2f((unsigned short)kk0[h][0]) + qh[h][1]*b2f((unsigned short)kk0[h][1])
                     + qh[h][2]*b2f((unsigned short)kk0[h][2]) + qh[h][3]*b2f((unsigned short)kk0[h][3])
                     + qh[h][4]*b2f((unsigned short)kk0[h][4]) + qh[h][5]*b2f((unsigned short)kk0[h][5])
                     + qh[h][6]*b2f((unsigned short)kk0[h][6]) + qh[h][7]*b2f((unsigned short)kk0[h][7]);
            float p1 = qh[h][0]*b2f((unsigned short)kk1[h][0]) + qh[h][1]*b2f((unsigned short)kk1[h][1])
                     + qh[h][2]*b2f((unsigned short)kk1[h][2]) + qh[h][3]*b2f((unsigned short)kk1[h][3])
                     + qh[h][4]*b2f((unsigned short)kk1[h][4]) + qh[h][5]*b2f((unsigned short)kk1[h][5])
                     + qh[h][6]*b2f((unsigned short)kk1[h][6]) + qh[h][7]*b2f((unsigned short)kk1[h][7]);
            p0 = dpp_sum16(p0);                  // VALU-only 16-lane sums
            p1 = dpp_sum16(p1);
            float sc0 = ok0 ? (p0 * INV_SQRT_D + qeI[h] * ee0) : -1e30f;
            float sc1 = ok1 ? (p1 * INV_SQRT_D + qeI[h] * ee1) : -1e30f;
            float a0 = __expf(fminf(sc0, 60.f));
            float a1 = __expf(fminf(sc1, 60.f));
            l_acc[h]  += a0 + a1;
            ew_acc[h] += a0 * ee0 + a1 * ee1;
            float al0[4], al1[4];
#pragma unroll
            for (int es = 0; es < 4; es++) {     // wave-uniform -> readlane (no DS)
                al0[es] = readlane_f(a0, es * 16);
                al1[es] = readlane_f(a1, es * 16);
            }
#pragma unroll
            for (int es = 0; es < 4; es++) {
                acc[h][0] += al0[es] * b2f_lo(vraw[h][es]) + al1[es] * b2f_lo(vraw[h][es + 4]);
                acc[h][1] += al0[es] * b2f_hi(vraw[h][es]) + al1[es] * b2f_hi(vraw[h][es + 4]);
            }
        }
        __builtin_amdgcn_s_setprio(0);
    }

    // reduce l/ew across the 4 subgroups (values replicated within subgroup)
    float rh[H][2];
#pragma unroll
    for (int h = 0; h < H; h++) {
        float l  = l_acc[h]  + __shfl_xor(l_acc[h], 16);
        float ew = ew_acc[h] + __shfl_xor(ew_acc[h], 16);
        l  += __shfl_xor(l, 32);
        ew += __shfl_xor(ew, 32);
        float invZ = (l > 0.f) ? 1.f / l : 0.f;
        rh[h][0] = (acc[h][0] + ew * We[h * DD + c0])     * invZ;
        rh[h][1] = (acc[h][1] + ew * We[h * DD + c0 + 1]) * invZ;
    }
    float r0, r1;
    if constexpr (MEANH) {
        r0 = 0.5f * (rh[0][0] + rh[H - 1][0]);
        r1 = 0.5f * (rh[0][1] + rh[H - 1][1]);
    } else {
        r0 = rh[0][0]; r1 = rh[0][1];
    }
    float2 sk = *(const float2*)&sio[(size_t)row * SSTR + c0];
    r0 += sk.x; r1 += sk.y;

    if constexpr (LNRELU) {
        float sum = r0 + r1, sq = r0 * r0 + r1 * r1;
#pragma unroll
        for (int off = 32; off; off >>= 1) { sum += __shfl_xor(sum, off); sq += __shfl_xor(sq, off); }
        float mu  = sum * (1.f / DD);
        float var = sq * (1.f / DD) - mu * mu;
        float rs  = rsqrtf(var + 1e-5f);
        r0 = fmaxf((r0 - mu) * rs, 0.f);
        r1 = fmaxf((r1 - mu) * rs, 0.f);
    }

    if constexpr (NCOLS == 0) {
        float2 res; res.x = r0; res.y = r1;
        *(float2*)&out[(size_t)row * DD + c0] = res;
    } else {
        // stage bf16 x-tile (8 real + 8 zero rows) in LDS, MFMA-project
        __hip_bfloat162 o;
        o.x = __float2bfloat16(r0);
        o.y = __float2bfloat16(r1);
        *(__hip_bfloat162*)&xs[wid][c0] = o;
        __syncthreads();   // all attn reads (q/skip/k/v) drained before writes

        int m16 = lane & 15, quad = lane >> 4;
        short8 a[4];
#pragma unroll
        for (int ks = 0; ks < 4; ks++)
            a[ks] = *(const short8*)&xs[m16][ks * 32 + quad * 8];

#pragma unroll 1
        for (int tile = wid; tile < NCOLS / 16; tile += 8) {
            int n0 = tile * 16;
            f32x4 pacc = {0.f, 0.f, 0.f, 0.f};
#pragma unroll
            for (int ks = 0; ks < 4; ks++) {
                const short8* bp = (const short8*)&Wt[(size_t)(n0 + m16) * DD + ks * 32 + quad * 8];
                pacc = __builtin_amdgcn_mfma_f32_16x16x32_bf16(a[ks], *bp, pacc, 0, 0, 0);
            }
            if (quad < 2) {                       // rows 0..7 are real
                if (n0 < HDN) {                                   // q: fp32 in place
#pragma unroll
                    for (int r = 0; r < 4; r++)
                        qio[(size_t)(row0 + quad * 4 + r) * QSTR + n0 + m16] = pacc[r];
                } else if (n0 < 2*HDN) {                          // k: bf16
                    int lc = n0 - HDN;
#pragma unroll
                    for (int r = 0; r < 4; r++)
                        kn[(size_t)(row0 + quad * 4 + r) * KVSO + lc + m16] = __float2bfloat16(pacc[r]);
                } else if (n0 < 3*HDN) {                          // v: bf16
                    int lc = n0 - 2*HDN;
#pragma unroll
                    for (int r = 0; r < 4; r++)
                        vn[(size_t)(row0 + quad * 4 + r) * KVSO + lc + m16] = __float2bfloat16(pacc[r]);
                } else {                                          // skip: fp32 in place
                    int lc = n0 - 3*HDN;
#pragma unroll
                    for (int r = 0; r < 4; r++)
                        sio[(size_t)(row0 + quad * 4 + r) * SSTR + lc + m16] = pacc[r];
                }
            }
        }
    }
}

// ---------------------------------------------------------------------------
extern "C" void kernel_launch(void* const* d_in, const int* in_sizes, int n_in,
                              void* d_out, int out_size, void* d_ws, size_t ws_size,
                              hipStream_t stream)
{
    const float* node = (const float*)d_in[0];
    const float* edge = (const float*)d_in[1];
    const float* A    = (const float*)d_in[2];
    const float* Wq[3] = {(const float*)d_in[3],  (const float*)d_in[8],  (const float*)d_in[13]};
    const float* Wk[3] = {(const float*)d_in[4],  (const float*)d_in[9],  (const float*)d_in[14]};
    const float* Wv[3] = {(const float*)d_in[5],  (const float*)d_in[10], (const float*)d_in[15]};
    const float* We[3] = {(const float*)d_in[6],  (const float*)d_in[11], (const float*)d_in[16]};
    const float* Ws[3] = {(const float*)d_in[7],  (const float*)d_in[12], (const float*)d_in[17]};

    // workspace carve (~18.5 MiB)
    char* p = (char*)d_ws;
    float*          q  = (float*)p;          p += (size_t)BN * QSTR * 4;
    float*          s  = (float*)p;          p += (size_t)BN * SSTR * 4;
    __hip_bfloat16* kA = (__hip_bfloat16*)p; p += (size_t)BN * 256 * 2;
    __hip_bfloat16* vA = (__hip_bfloat16*)p; p += (size_t)BN * 256 * 2;
    __hip_bfloat16* kB = (__hip_bfloat16*)p; p += (size_t)BN * 128 * 2;
    __hip_bfloat16* vB = (__hip_bfloat16*)p; p += (size_t)BN * 128 * 2;
    __hip_bfloat16* Wt1 = (__hip_bfloat16*)p; p += (size_t)512 * DD * 2;
    __hip_bfloat16* Wt2 = (__hip_bfloat16*)p; p += (size_t)896 * DD * 2;
    unsigned short* degc   = (unsigned short*)p; p += (size_t)BN * 8 * 2;
    unsigned short* colsc  = (unsigned short*)p; p += (size_t)BN * 8 * CCAP * 2;
    float*          evalsc = (float*)p;          p += (size_t)BN * 8 * CCAP * 4;

    prep<<<1024 + 1408 + BN / 16, 256, 0, stream>>>(
        A, edge, node,
        Wq[0], Wk[0], Wv[0], Ws[0],
        Wq[1], Wk[1], Wv[1], Ws[1],
        Wq[2], Wk[2], Wv[2], Ws[2],
        Wt1, Wt2, q, kA, vA, s, degc, colsc, evalsc);

    // app sequence l = {0,1,2,1,2,1,2}; each kernel = attn(l) + proj(next l)
    // 512-thread blocks, grid BN/8 = 512 (>= 2 blocks/CU: degree-tail overlap).
    fused_attn<1, 8, false, true, 512, 128, 256, 128><<<BN / 8, 512, 0, stream>>>(   // l0 -> proj l1
        q, kA, vA, s, degc, colsc, evalsc, We[0], Wt1, kB, vB, nullptr);
    fused_attn<1, 8, false, true, 896, 256, 128, 256><<<BN / 8, 512, 0, stream>>>(   // l1 -> proj l2
        q, kB, vB, s, degc, colsc, evalsc, We[1], Wt2, kA, vA, nullptr);
    fused_attn<2, 4, true, false, 512, 128, 256, 128><<<BN / 8, 512, 0, stream>>>(   // l2 -> proj l1
        q, kA, vA, s, degc, colsc, evalsc, We[2], Wt1, kB, vB, nullptr);
    fused_attn<1, 8, false, true, 896, 256, 128, 256><<<BN / 8, 512, 0, stream>>>(   // l1 -> proj l2
        q, kB, vB, s, degc, colsc, evalsc, We[1], Wt2, kA, vA, nullptr);
    fused_attn<2, 4, true, false, 512, 128, 256, 128><<<BN / 8, 512, 0, stream>>>(   // l2 -> proj l1
        q, kA, vA, s, degc, colsc, evalsc, We[2], Wt1, kB, vB, nullptr);
    fused_attn<1, 8, false, true, 896, 256, 128, 256><<<BN / 8, 512, 0, stream>>>(   // l1 -> proj l2
        q, kB, vB, s, degc, colsc, evalsc, We[1], Wt2, kA, vA, nullptr);
    fused_attn<2, 4, true, false, 0, 0, 256, 0><<<BN / 8, 512, 0, stream>>>(         // l2 -> output
        q, kA, vA, s, degc, colsc, evalsc, We[2], nullptr, nullptr, nullptr, (float*)d_out);
}

// Round 19
// 279.669 us; speedup vs baseline: 1.0842x; 1.0842x over previous
//
#include <hip/hip_runtime.h>
#include <hip/hip_bf16.h>

#define BB 2
#define NN 2048
#define DD 128
#define BN (BB*NN)
#define CAP 128
#define TD 32
#define CCAP 32
#define QSTR 256
#define SSTR 128
#define INV_SQRT_D 0.08838834764831845f

typedef __attribute__((ext_vector_type(8))) short short8;
typedef __attribute__((ext_vector_type(4))) float f32x4;

__device__ inline float b2f(unsigned short u) {
    union { unsigned int i; float f; } c; c.i = (unsigned int)u << 16; return c.f;
}
__device__ inline float b2f_hi(unsigned int raw) {
    union { unsigned int i; float f; } c; c.i = raw & 0xffff0000u; return c.f;
}
__device__ inline float b2f_lo(unsigned int raw) {
    union { unsigned int i; float f; } c; c.i = raw << 16; return c.f;
}

// 16-lane sum, VALU-only (DPP): quad xor1, quad xor2, row_ror:4, row_ror:8.
__device__ inline float dpp_sum16(float x) {
    int v;
    v = __builtin_bit_cast(int, x);
    x += __builtin_bit_cast(float, __builtin_amdgcn_update_dpp(0, v, 0xB1,  0xF, 0xF, true)); // quad_perm [1,0,3,2]
    v = __builtin_bit_cast(int, x);
    x += __builtin_bit_cast(float, __builtin_amdgcn_update_dpp(0, v, 0x4E,  0xF, 0xF, true)); // quad_perm [2,3,0,1]
    v = __builtin_bit_cast(int, x);
    x += __builtin_bit_cast(float, __builtin_amdgcn_update_dpp(0, v, 0x124, 0xF, 0xF, true)); // row_ror:4
    v = __builtin_bit_cast(int, x);
    x += __builtin_bit_cast(float, __builtin_amdgcn_update_dpp(0, v, 0x128, 0xF, 0xF, true)); // row_ror:8
    return x;
}

// wave-uniform broadcast of lane `l` (compile-time) -> SGPR, no DS op
__device__ inline float readlane_f(float x, int l) {
    return __builtin_bit_cast(float, __builtin_amdgcn_readlane(__builtin_bit_cast(int, x), l));
}

// ---------------------------------------------------------------------------
// Merged prep kernel. CSR SEGMENTED PER CHUNK: each (row, chunk) owns a
// fixed 32-entry segment (colsc/evalsc) + a non-atomic count (degc) ->
// NO global atomics and NO deg memset. Per-chunk cap 32 is 8.9 sigma above
// the Binomial(256,0.03) mean 7.7 -> edge set unchanged in practice.
//   bid < 1024         : CSR build, TD=32 dst stripes x 8 src chunks
//   1024 <= bid < 2432 : weight transposes Wt1 (512) / Wt2 (896)
//   2432 <= bid < 2688 : layer-0 rank-1 projection (256 row-tiles)
// ---------------------------------------------------------------------------
__global__ __launch_bounds__(256) void prep(
    const float* __restrict__ A, const float* __restrict__ edge,
    const float* __restrict__ node,
    const float* __restrict__ Wq0, const float* __restrict__ Wk0,
    const float* __restrict__ Wv0, const float* __restrict__ Ws0,
    const float* __restrict__ Wq1, const float* __restrict__ Wk1,
    const float* __restrict__ Wv1, const float* __restrict__ Ws1,
    const float* __restrict__ Wq2, const float* __restrict__ Wk2,
    const float* __restrict__ Wv2, const float* __restrict__ Ws2,
    __hip_bfloat16* __restrict__ Wt1, __hip_bfloat16* __restrict__ Wt2,
    float* __restrict__ q, __hip_bfloat16* __restrict__ kA,
    __hip_bfloat16* __restrict__ vA, float* __restrict__ s,
    unsigned short* __restrict__ degc,      // [BN][8]
    unsigned short* __restrict__ colsc,     // [BN][8][CCAP]
    float* __restrict__ evalsc)             // [BN][8][CCAP]
{
    __shared__ int   cnt[TD];
    __shared__ int   csh[TD][CCAP];
    __shared__ float esh[TD][CCAP];
    __shared__ float xnode[16];

    int bid = blockIdx.x;
    int tid = threadIdx.x;

    if (bid < 1024) {
        // ---- CSR build: 32 dst cols x 256 src rows per block ----
        int b     = bid >> 9;
        int r     = bid & 511;
        int dst0  = (r >> 3) * TD;
        int chunk = r & 7;

        if (tid < TD) cnt[tid] = 0;
        __syncthreads();

        int srcOff = tid >> 3;
        int dOff   = (tid & 7) * 4;
        int src0   = chunk * 256;
        const size_t base = (size_t)b * NN * NN + (size_t)src0 * NN + dst0 + dOff;

#pragma unroll 2
        for (int s0 = 0; s0 < 256; s0 += 32) {
            int srel = s0 + srcOff;
            float4 a4 = *(const float4*)&A[base + (size_t)srel * NN];
            float4 e4 = *(const float4*)&edge[base + (size_t)srel * NN];
            int gsrc = b * NN + src0 + srel;
            float av[4] = {a4.x, a4.y, a4.z, a4.w};
            float ev[4] = {e4.x, e4.y, e4.z, e4.w};
#pragma unroll
            for (int u = 0; u < 4; u++) {
                if (av[u] != 0.f) {
                    int d = dOff + u;
                    int slot = atomicAdd(&cnt[d], 1);   // LDS atomic only
                    if (slot < CCAP) { csh[d][slot] = gsrc; esh[d][slot] = ev[u] * av[u]; }
                }
            }
        }
        __syncthreads();

        if (tid < TD) {
            int row = b * NN + dst0 + tid;
            degc[(size_t)row * 8 + chunk] = (unsigned short)min(cnt[tid], CCAP);
        }

        for (int idx = tid; idx < TD * CCAP; idx += 256) {
            int d = idx >> 5, i = idx & (CCAP - 1);
            if (i < min(cnt[d], CCAP)) {
                size_t seg = ((size_t)(b * NN + dst0 + d) * 8 + chunk) * CCAP;
                colsc [seg + i] = (unsigned short)csh[d][i];
                evalsc[seg + i] = esh[d][i];
            }
        }
    } else if (bid < 1024 + 1408) {
        int c = bid - 1024;
        if (tid < DD) {
            const float *Wq, *Wk, *Wv, *Ws; __hip_bfloat16* Wt; int n, HD;
            if (c < 512) { Wq = Wq1; Wk = Wk1; Wv = Wv1; Ws = Ws1; Wt = Wt1; n = c;       HD = DD;     }
            else         { Wq = Wq2; Wk = Wk2; Wv = Wv2; Ws = Ws2; Wt = Wt2; n = c - 512; HD = 2 * DD; }
            const float* src; int ld; int col;
            if      (n < HD)     { src = Wq; col = n;          ld = HD; }
            else if (n < 2*HD)   { src = Wk; col = n - HD;     ld = HD; }
            else if (n < 3*HD)   { src = Wv; col = n - 2*HD;   ld = HD; }
            else                 { src = Ws; col = n - 3*HD;   ld = DD; }
            Wt[(size_t)n * DD + tid] = __float2bfloat16(src[(size_t)tid * ld + col]);
        }
    } else {
        int row0 = (bid - (1024 + 1408)) * 16;
        if (tid < 16) xnode[tid] = node[row0 + tid];
        __syncthreads();
        for (int i = tid; i < 16 * 512; i += 256) {
            int r = i >> 9, col = i & 511;
            float xv = xnode[r];
            if (col < DD) {
                q[(size_t)(row0 + r) * QSTR + col] = xv * Wq0[col];
            } else if (col < 2*DD) {
                int lc = col - DD;
                kA[(size_t)(row0 + r) * 256 + lc] = __float2bfloat16(xv * Wk0[lc]);
            } else if (col < 3*DD) {
                int lc = col - 2*DD;
                vA[(size_t)(row0 + r) * 256 + lc] = __float2bfloat16(xv * Wv0[lc]);
            } else {
                int lc = col - 3*DD;
                s[(size_t)(row0 + r) * SSTR + lc] = xv * Ws0[lc];
            }
        }
    }
}

// ---------------------------------------------------------------------------
// Fused sparse attention + next-layer projection — round-17 configuration
// (session best, 280.0 us): 16 rows / 1024 threads (r7+r18 both measured the
// 8-row geometry losing), segmented CSR header (prefix + gather-compact),
// pad+int4 CSR reads, k-first 32-bit-offset gathers, DPP reduces, readlane
// broadcasts, setprio, MINW split (H=1: 8, H=2: 4).
// ---------------------------------------------------------------------------
template<int H, int MINW, bool MEANH, bool LNRELU, int NCOLS, int HDN, int KVSI, int KVSO>
__global__ __launch_bounds__(1024, MINW) void fused_attn(
    float* qio,                                   // in/out, stride QSTR
    const __hip_bfloat16* __restrict__ k,         // stride KVSI
    const __hip_bfloat16* __restrict__ v,         // stride KVSI
    float* sio,                                   // in/out, stride SSTR
    const unsigned short* __restrict__ degc,      // [BN][8]
    const unsigned short* __restrict__ colsc,     // [BN][8][CCAP]
    const float* __restrict__ evalsc,             // [BN][8][CCAP]
    const float* __restrict__ We,
    const __hip_bfloat16* __restrict__ Wt,
    __hip_bfloat16* __restrict__ kn, __hip_bfloat16* __restrict__ vn, // stride KVSO
    float* __restrict__ out)
{
    const int HD = H * DD;
    constexpr unsigned KROWB = (unsigned)(KVSI * 2);   // bytes per k/v row (512 or 256, pow2)
    int wid  = threadIdx.x >> 6;       // 0..15
    int lane = threadIdx.x & 63;
    int row0 = blockIdx.x * 16;
    int row  = row0 + wid;
    int sub  = lane >> 4;
    int s    = lane & 15;
    int c0   = lane * 2;

    __shared__ int            jc_s[16][CAP];
    __shared__ float          ev_s[16][CAP];
    __shared__ __hip_bfloat16 xs[16][136];   // +8 bf16 pad (16B-aligned rows)
    int*   jc = jc_s[wid];
    float* ev = ev_s[wid];

    // ---- segmented CSR load: counts -> prefix -> gather-compact ----
    int dg;
    {
        const unsigned short* dcp = &degc[(size_t)row * 8];
        int cnt8[8], offs[8], off = 0;
#pragma unroll
        for (int c = 0; c < 8; c++) cnt8[c] = (int)dcp[c];
#pragma unroll
        for (int c = 0; c < 8; c++) { offs[c] = off; off += cnt8[c]; }
        dg = min(off, CAP);
        const size_t segb = (size_t)row * 8 * CCAP;
#pragma unroll
        for (int it = 0; it < 4; it++) {
            int i = it * 64 + lane;
            int c = i >> 5, m = i & (CCAP - 1);
            if (m < cnt8[c]) {
                int d = offs[c] + m;
                if (d < CAP) {
                    jc[d] = (int)colsc[segb + c * CCAP + m];
                    ev[d] = evalsc[segb + c * CCAP + m];
                }
            }
        }
    }
    int dgp = (dg + 7) & ~7;             // padded bound (multiple of 8)
    if (lane == 0 && dg > 0) {
        int jf = jc[0];
        for (int m = dg; m < dgp; m++) { jc[m] = jf; ev[m] = 0.f; }
    }
    // wave-private LDS: no barrier needed (compiler inserts lgkmcnt waits)

    const char* kc = (const char*)k;
    const char* vc = (const char*)v;
    const unsigned kLaneOff = (unsigned)(s * 16);      // s*8 bf16 = 16 B
    const unsigned vLaneOff = (unsigned)(c0 * 2);      // c0 bf16 = c0*2 B

    float qh[H][8];
    float qeI[H];
#pragma unroll
    for (int h = 0; h < H; h++) {
        const float* qp = &qio[(size_t)row * QSTR + h * DD + s * 8];
        const float* wp = &We[h * DD + s * 8];
        float pe = 0.f;
#pragma unroll
        for (int t = 0; t < 8; t++) { qh[h][t] = qp[t]; pe += qp[t] * wp[t]; }
        qeI[h] = dpp_sum16(pe) * INV_SQRT_D;
    }

    float l_acc[H], ew_acc[H], acc[H][2];
#pragma unroll
    for (int h = 0; h < H; h++) { l_acc[h] = 0.f; ew_acc[h] = 0.f; acc[h][0] = 0.f; acc[h][1] = 0.f; }

    for (int m0 = 0; m0 < dgp; m0 += 8) {
        int   e0  = m0 + sub,  e1 = m0 + 4 + sub;
        bool  ok0 = e0 < dg,   ok1 = e1 < dg;
        float ee0 = ev[e0],    ee1 = ev[e1];     // pad region holds 0 (unused: alpha=0)

        // 32-bit byte offsets (KROWB is pow2 -> shift+add; no 64-bit muls)
        unsigned ko0 = (unsigned)jc[e0] * KROWB + kLaneOff;
        unsigned ko1 = (unsigned)jc[e1] * KROWB + kLaneOff;

        int4 j4a = *(const int4*)&jc[m0];        // vectorized CSR reads (pad = jc[0])
        int4 j4b = *(const int4*)&jc[m0 + 4];
        unsigned vo[8] = {
            (unsigned)j4a.x * KROWB + vLaneOff, (unsigned)j4a.y * KROWB + vLaneOff,
            (unsigned)j4a.z * KROWB + vLaneOff, (unsigned)j4a.w * KROWB + vLaneOff,
            (unsigned)j4b.x * KROWB + vLaneOff, (unsigned)j4b.y * KROWB + vLaneOff,
            (unsigned)j4b.z * KROWB + vLaneOff, (unsigned)j4b.w * KROWB + vLaneOff };

        // k gathers FIRST (consumed first by the dot; keeps v loads in flight);
        // per-h displacement (h*256 B) is a compile-time immediate
        short8 kk0[H], kk1[H];
#pragma unroll
        for (int h = 0; h < H; h++) {
            kk0[h] = *(const short8*)(kc + (size_t)(ko0 + (unsigned)(h * 256)));
            kk1[h] = *(const short8*)(kc + (size_t)(ko1 + (unsigned)(h * 256)));
        }
        // v gathers
        unsigned int vraw[H][8];
#pragma unroll
        for (int h = 0; h < H; h++)
#pragma unroll
            for (int es = 0; es < 8; es++)
                vraw[h][es] = *(const unsigned int*)(vc + (size_t)(vo[es] + (unsigned)(h * 256)));

        __builtin_amdgcn_s_setprio(1);
#pragma unroll
        for (int h = 0; h < H; h++) {
            float p0 = qh[h][0]*b2f((unsigned short)kk0[h][0]) + qh[h][1]*b2f((unsigned short)kk0[h][1])
                     + qh[h][2]*b2f((unsigned short)kk0[h][2]) + qh[h][3]*b2f((unsigned short)kk0[h][3])
                     + qh[h][4]*b2f((unsigned short)kk0[h][4]) + qh[h][5]*b2f((unsigned short)kk0[h][5])
                     + qh[h][6]*b2f((unsigned short)kk0[h][6]) + qh[h][7]*b2f((unsigned short)kk0[h][7]);
            float p1 = qh[h][0]*b2f((unsigned short)kk1[h][0]) + qh[h][1]*b2f((unsigned short)kk1[h][1])
                     + qh[h][2]*b2f((unsigned short)kk1[h][2]) + qh[h][3]*b2f((unsigned short)kk1[h][3])
                     + qh[h][4]*b2f((unsigned short)kk1[h][4]) + qh[h][5]*b2f((unsigned short)kk1[h][5])
                     + qh[h][6]*b2f((unsigned short)kk1[h][6]) + qh[h][7]*b2f((unsigned short)kk1[h][7]);
            p0 = dpp_sum16(p0);                  // VALU-only 16-lane sums
            p1 = dpp_sum16(p1);
            float sc0 = ok0 ? (p0 * INV_SQRT_D + qeI[h] * ee0) : -1e30f;
            float sc1 = ok1 ? (p1 * INV_SQRT_D + qeI[h] * ee1) : -1e30f;
            float a0 = __expf(fminf(sc0, 60.f));
            float a1 = __expf(fminf(sc1, 60.f));
            l_acc[h]  += a0 + a1;
            ew_acc[h] += a0 * ee0 + a1 * ee1;
            float al0[4], al1[4];
#pragma unroll
            for (int es = 0; es < 4; es++) {     // wave-uniform -> readlane (no DS)
                al0[es] = readlane_f(a0, es * 16);
                al1[es] = readlane_f(a1, es * 16);
            }
#pragma unroll
            for (int es = 0; es < 4; es++) {
                acc[h][0] += al0[es] * b2f_lo(vraw[h][es]) + al1[es] * b2f_lo(vraw[h][es + 4]);
                acc[h][1] += al0[es] * b2f_hi(vraw[h][es]) + al1[es] * b2f_hi(vraw[h][es + 4]);
            }
        }
        __builtin_amdgcn_s_setprio(0);
    }

    // reduce l/ew across the 4 subgroups (values replicated within subgroup)
    float rh[H][2];
#pragma unroll
    for (int h = 0; h < H; h++) {
        float l  = l_acc[h]  + __shfl_xor(l_acc[h], 16);
        float ew = ew_acc[h] + __shfl_xor(ew_acc[h], 16);
        l  += __shfl_xor(l, 32);
        ew += __shfl_xor(ew, 32);
        float invZ = (l > 0.f) ? 1.f / l : 0.f;
        rh[h][0] = (acc[h][0] + ew * We[h * DD + c0])     * invZ;
        rh[h][1] = (acc[h][1] + ew * We[h * DD + c0 + 1]) * invZ;
    }
    float r0, r1;
    if constexpr (MEANH) {
        r0 = 0.5f * (rh[0][0] + rh[H - 1][0]);
        r1 = 0.5f * (rh[0][1] + rh[H - 1][1]);
    } else {
        r0 = rh[0][0]; r1 = rh[0][1];
    }
    float2 sk = *(const float2*)&sio[(size_t)row * SSTR + c0];
    r0 += sk.x; r1 += sk.y;

    if constexpr (LNRELU) {
        float sum = r0 + r1, sq = r0 * r0 + r1 * r1;
#pragma unroll
        for (int off = 32; off; off >>= 1) { sum += __shfl_xor(sum, off); sq += __shfl_xor(sq, off); }
        float mu  = sum * (1.f / DD);
        float var = sq * (1.f / DD) - mu * mu;
        float rs  = rsqrtf(var + 1e-5f);
        r0 = fmaxf((r0 - mu) * rs, 0.f);
        r1 = fmaxf((r1 - mu) * rs, 0.f);
    }

    if constexpr (NCOLS == 0) {
        float2 res; res.x = r0; res.y = r1;
        *(float2*)&out[(size_t)row * DD + c0] = res;
    } else {
        // stage bf16 x-tile in LDS, then MFMA-project into next-layer buffers
        __hip_bfloat162 o;
        o.x = __float2bfloat16(r0);
        o.y = __float2bfloat16(r1);
        *(__hip_bfloat162*)&xs[wid][c0] = o;
        __syncthreads();   // all attn reads (q/skip/k/v) drained before writes

        int m16 = lane & 15, quad = lane >> 4;
        short8 a[4];
#pragma unroll
        for (int ks = 0; ks < 4; ks++)
            a[ks] = *(const short8*)&xs[m16][ks * 32 + quad * 8];

#pragma unroll 1
        for (int tile = wid; tile < NCOLS / 16; tile += 16) {
            int n0 = tile * 16;
            f32x4 pacc = {0.f, 0.f, 0.f, 0.f};
#pragma unroll
            for (int ks = 0; ks < 4; ks++) {
                const short8* bp = (const short8*)&Wt[(size_t)(n0 + m16) * DD + ks * 32 + quad * 8];
                pacc = __builtin_amdgcn_mfma_f32_16x16x32_bf16(a[ks], *bp, pacc, 0, 0, 0);
            }
            if (n0 < HDN) {                                   // q: fp32 in place
#pragma unroll
                for (int r = 0; r < 4; r++)
                    qio[(size_t)(row0 + quad * 4 + r) * QSTR + n0 + m16] = pacc[r];
            } else if (n0 < 2*HDN) {                          // k: bf16
                int lc = n0 - HDN;
#pragma unroll
                for (int r = 0; r < 4; r++)
                    kn[(size_t)(row0 + quad * 4 + r) * KVSO + lc + m16] = __float2bfloat16(pacc[r]);
            } else if (n0 < 3*HDN) {                          // v: bf16
                int lc = n0 - 2*HDN;
#pragma unroll
                for (int r = 0; r < 4; r++)
                    vn[(size_t)(row0 + quad * 4 + r) * KVSO + lc + m16] = __float2bfloat16(pacc[r]);
            } else {                                          // skip: fp32 in place
                int lc = n0 - 3*HDN;
#pragma unroll
                for (int r = 0; r < 4; r++)
                    sio[(size_t)(row0 + quad * 4 + r) * SSTR + lc + m16] = pacc[r];
            }
        }
    }
}

// ---------------------------------------------------------------------------
extern "C" void kernel_launch(void* const* d_in, const int* in_sizes, int n_in,
                              void* d_out, int out_size, void* d_ws, size_t ws_size,
                              hipStream_t stream)
{
    const float* node = (const float*)d_in[0];
    const float* edge = (const float*)d_in[1];
    const float* A    = (const float*)d_in[2];
    const float* Wq[3] = {(const float*)d_in[3],  (const float*)d_in[8],  (const float*)d_in[13]};
    const float* Wk[3] = {(const float*)d_in[4],  (const float*)d_in[9],  (const float*)d_in[14]};
    const float* Wv[3] = {(const float*)d_in[5],  (const float*)d_in[10], (const float*)d_in[15]};
    const float* We[3] = {(const float*)d_in[6],  (const float*)d_in[11], (const float*)d_in[16]};
    const float* Ws[3] = {(const float*)d_in[7],  (const float*)d_in[12], (const float*)d_in[17]};

    // workspace carve (~18.5 MiB): q 4 | s 2 | kA/vA 4 | kB/vB 2 | Wt 0.35
    //   degc 64 KB | colsc 2 MB | evalsc 4 MB
    char* p = (char*)d_ws;
    float*          q  = (float*)p;          p += (size_t)BN * QSTR * 4;
    float*          s  = (float*)p;          p += (size_t)BN * SSTR * 4;
    __hip_bfloat16* kA = (__hip_bfloat16*)p; p += (size_t)BN * 256 * 2;
    __hip_bfloat16* vA = (__hip_bfloat16*)p; p += (size_t)BN * 256 * 2;
    __hip_bfloat16* kB = (__hip_bfloat16*)p; p += (size_t)BN * 128 * 2;
    __hip_bfloat16* vB = (__hip_bfloat16*)p; p += (size_t)BN * 128 * 2;
    __hip_bfloat16* Wt1 = (__hip_bfloat16*)p; p += (size_t)512 * DD * 2;
    __hip_bfloat16* Wt2 = (__hip_bfloat16*)p; p += (size_t)896 * DD * 2;
    unsigned short* degc   = (unsigned short*)p; p += (size_t)BN * 8 * 2;
    unsigned short* colsc  = (unsigned short*)p; p += (size_t)BN * 8 * CCAP * 2;
    float*          evalsc = (float*)p;          p += (size_t)BN * 8 * CCAP * 4;

    prep<<<1024 + 1408 + BN / 16, 256, 0, stream>>>(
        A, edge, node,
        Wq[0], Wk[0], Wv[0], Ws[0],
        Wq[1], Wk[1], Wv[1], Ws[1],
        Wq[2], Wk[2], Wv[2], Ws[2],
        Wt1, Wt2, q, kA, vA, s, degc, colsc, evalsc);

    // app sequence l = {0,1,2,1,2,1,2}; each kernel = attn(l) + proj(next l)
    // H=1 layers: MINW=8 (2 blocks/CU, VGPR<=64). H=2 layers: MINW=4.
    fused_attn<1, 8, false, true, 512, 128, 256, 128><<<BN / 16, 1024, 0, stream>>>(   // l0 -> proj l1
        q, kA, vA, s, degc, colsc, evalsc, We[0], Wt1, kB, vB, nullptr);
    fused_attn<1, 8, false, true, 896, 256, 128, 256><<<BN / 16, 1024, 0, stream>>>(   // l1 -> proj l2
        q, kB, vB, s, degc, colsc, evalsc, We[1], Wt2, kA, vA, nullptr);
    fused_attn<2, 4, true, false, 512, 128, 256, 128><<<BN / 16, 1024, 0, stream>>>(   // l2 -> proj l1
        q, kA, vA, s, degc, colsc, evalsc, We[2], Wt1, kB, vB, nullptr);
    fused_attn<1, 8, false, true, 896, 256, 128, 256><<<BN / 16, 1024, 0, stream>>>(   // l1 -> proj l2
        q, kB, vB, s, degc, colsc, evalsc, We[1], Wt2, kA, vA, nullptr);
    fused_attn<2, 4, true, false, 512, 128, 256, 128><<<BN / 16, 1024, 0, stream>>>(   // l2 -> proj l1
        q, kA, vA, s, degc, colsc, evalsc, We[2], Wt1, kB, vB, nullptr);
    fused_attn<1, 8, false, true, 896, 256, 128, 256><<<BN / 16, 1024, 0, stream>>>(   // l1 -> proj l2
        q, kB, vB, s, degc, colsc, evalsc, We[1], Wt2, kA, vA, nullptr);
    fused_attn<2, 4, true, false, 0, 0, 256, 0><<<BN / 16, 1024, 0, stream>>>(         // l2 -> output
        q, kA, vA, s, degc, colsc, evalsc, We[2], nullptr, nullptr, nullptr, (float*)d_out);
}